// Round 5
// baseline (794.499 us; speedup 1.0000x reference)
//
#include <hip/hip_runtime.h>

#define NN 50000
#define NE 800000
#define ET (NE + NN)   // 850000 edges incl. self-loops
#define SCAN_B 256
#define NBLK ((NN + SCAN_B - 1) / SCAN_B)   // 196
#define DCAP1 256      // max degree on fast path, layer1
#define DCAP2 512      // max degree on fast path, layer2

typedef unsigned short u16;
typedef unsigned int u32;

__device__ __forceinline__ float lrelu(float a) { return a > 0.f ? a : 0.2f * a; }
// f32 -> bf16 bits, round-to-nearest-even
__device__ __forceinline__ u16 f2bf(float f) {
    u32 b = __float_as_uint(f);
    b += 0x7FFFu + ((b >> 16) & 1u);
    return (u16)(b >> 16);
}
__device__ __forceinline__ float bf2f(u16 u) {
    return __uint_as_float(((u32)u) << 16);
}

// ---- init: zero degrees, d_out = b2 ----
__global__ void k_init(int* __restrict__ deg, const float* __restrict__ b2,
                       float* __restrict__ out) {
    int i = blockIdx.x * blockDim.x + threadIdx.x;
    if (i < NN)  deg[i] = 0;
    if (i < 128) out[i] = b2[i];
}

// ---- CSR build: degree count ----
__global__ void k_deg(const int* __restrict__ ei, int* __restrict__ deg) {
    int e = blockIdx.x * blockDim.x + threadIdx.x;
    if (e >= ET) return;
    int d = (e < NE) ? ei[NE + e] : e - NE;
    atomicAdd(deg + d, 1);
}

// ---- scan stage A ----
__global__ __launch_bounds__(SCAN_B) void k_scan_a(const int* __restrict__ deg,
                                                   int* __restrict__ off,
                                                   int* __restrict__ bsum) {
    __shared__ int sh[SCAN_B];
    int t = threadIdx.x, i = blockIdx.x * SCAN_B + t;
    int v = (i < NN) ? deg[i] : 0;
    sh[t] = v;
    __syncthreads();
#pragma unroll
    for (int s = 1; s < SCAN_B; s <<= 1) {
        int u = (t >= s) ? sh[t - s] : 0;
        __syncthreads();
        sh[t] += u;
        __syncthreads();
    }
    if (i < NN) off[i] = sh[t] - v;
    if (t == SCAN_B - 1) bsum[blockIdx.x] = sh[t];
}

// ---- scan stage B ----
__global__ __launch_bounds__(SCAN_B) void k_scan_b(int* __restrict__ bsum,
                                                   int* __restrict__ off) {
    __shared__ int sh[SCAN_B];
    int t = threadIdx.x;
    int v = (t < NBLK) ? bsum[t] : 0;
    sh[t] = v;
    __syncthreads();
#pragma unroll
    for (int s = 1; s < SCAN_B; s <<= 1) {
        int u = (t >= s) ? sh[t - s] : 0;
        __syncthreads();
        sh[t] += u;
        __syncthreads();
    }
    if (t < NBLK) bsum[t] = sh[t] - v;
    if (t == 0) off[NN] = ET;
}

// ---- scan stage C ----
__global__ __launch_bounds__(SCAN_B) void k_scan_c(int* __restrict__ off,
                                                   const int* __restrict__ bsum,
                                                   int* __restrict__ cur) {
    int i = blockIdx.x * SCAN_B + threadIdx.x;
    if (i >= NN) return;
    int o = off[i] + bsum[blockIdx.x];
    off[i] = o;
    cur[i] = o;
}

// ---- CSR fill ----
__global__ void k_fill(const int* __restrict__ ei, int* __restrict__ cur,
                       int* __restrict__ csr) {
    int e = blockIdx.x * blockDim.x + threadIdx.x;
    if (e >= ET) return;
    int s, d;
    if (e < NE) { s = ei[e]; d = ei[NE + e]; } else { s = d = e - NE; }
    int pos = atomicAdd(cur + d, 1);
    csr[pos] = s;
}

// ---- layer1 node transform: h1 = x@W1 (bf16 out) ; attention dots (f32) ----
__global__ __launch_bounds__(128) void k_node1(
        const float* __restrict__ x, const float* __restrict__ W1,
        const float* __restrict__ as1, const float* __restrict__ ad1,
        u16* __restrict__ hbf, float* __restrict__ asrc, float* __restrict__ adst) {
    int n = blockIdx.x, c = threadIdx.x;
    float x0 = x[2 * n], x1 = x[2 * n + 1];
    float hv = fmaf(x0, W1[c], x1 * W1[128 + c]);
    hbf[(size_t)n * 128 + c] = f2bf(hv);
    float ps = hv * as1[c], pd = hv * ad1[c];
#pragma unroll
    for (int m = 16; m >= 1; m >>= 1) {
        ps += __shfl_xor(ps, m);
        pd += __shfl_xor(pd, m);
    }
    if ((c & 31) == 0) {
        int hd = c >> 5;
        asrc[n * 4 + hd] = ps;
        adst[n * 4 + hd] = pd;
    }
}

// ---- layer1 gather-aggregate: edge-parallel softmax in LDS, heads=4 ----
__global__ __launch_bounds__(128) void k_agg1v(
        const int* __restrict__ off, const int* __restrict__ csr,
        const float* __restrict__ asrc, const float* __restrict__ adst,
        const u16* __restrict__ hbf, float* __restrict__ ob) {
    __shared__ float2 pair[4][DCAP1];      // {ex, src_bits}, [head][edge]
    __shared__ float redm[4], redd[4];
    int n = blockIdx.x, t = threadIdx.x;
    int hd = t >> 5, l = t & 31;
    int e0 = off[n], deg = off[n + 1] - e0;
    float ad = adst[n * 4 + hd];

    if (deg <= DCAP1) {
        float mymax = -1e30f;
        for (int e = l; e < deg; e += 32) {
            int s = csr[e0 + e];
            float al = lrelu(asrc[s * 4 + hd] + ad);
            pair[hd][e] = make_float2(al, __int_as_float(s));
            mymax = fmaxf(mymax, al);
        }
#pragma unroll
        for (int m = 16; m >= 1; m >>= 1) mymax = fmaxf(mymax, __shfl_xor(mymax, m));
        if (l == 0) redm[hd] = mymax;
        __syncthreads();
        float amax = redm[hd];
        float myden = 0.f;
        for (int e = l; e < deg; e += 32) {
            float ex = __expf(pair[hd][e].x - amax);
            pair[hd][e].x = ex;
            myden += ex;
        }
#pragma unroll
        for (int m = 16; m >= 1; m >>= 1) myden += __shfl_xor(myden, m);
        if (l == 0) redd[hd] = myden;
        __syncthreads();
        float inv = 1.f / (redd[hd] + 1e-16f);
        const u16* hc = hbf + t;
        float acc = 0.f;
#pragma unroll 4
        for (int e = 0; e < deg; ++e) {
            float2 p = pair[hd][e];
            acc = fmaf(p.x, bf2f(hc[(size_t)__float_as_int(p.y) * 128]), acc);
        }
        ob[(size_t)n * 128 + t] = acc * inv;
    } else {
        float amax = -1e30f;
        for (int e = e0; e < e0 + deg; ++e) {
            int s = csr[e];
            amax = fmaxf(amax, lrelu(asrc[s * 4 + hd] + ad));
        }
        float den = 0.f, acc = 0.f;
        for (int e = e0; e < e0 + deg; ++e) {
            int s = csr[e];
            float ex = __expf(lrelu(asrc[s * 4 + hd] + ad) - amax);
            den += ex;
            acc = fmaf(ex, bf2f(hbf[(size_t)s * 128 + t]), acc);
        }
        ob[(size_t)n * 128 + t] = acc / (den + 1e-16f);
    }
}

// ---- layer2 node transform, register-tiled GEMM; h2 out bf16 ----
__global__ __launch_bounds__(256) void k_node2t(
        const float* __restrict__ ob, const float* __restrict__ b1,
        const float* __restrict__ W2, const float* __restrict__ as2,
        const float* __restrict__ ad2, u16* __restrict__ h2bf,
        float* __restrict__ asrc, float* __restrict__ adst) {
    __shared__ float Wl[32][128];
    __shared__ float xt[32][128];
    int t = threadIdx.x;
    int tc = t & 31, tr = t >> 5;
    int n0 = blockIdx.x * 32;

#pragma unroll
    for (int i = 0; i < 4; ++i) {
        int f4 = t + i * 256;
        int r = f4 >> 5, c4 = f4 & 31;
        float4 v = make_float4(0.f, 0.f, 0.f, 0.f);
        int n = n0 + r;
        if (n < NN) {
            v = *(const float4*)(ob + (size_t)n * 128 + c4 * 4);
            float4 bb = *(const float4*)(b1 + c4 * 4);
            v.x = fmaxf(v.x + bb.x, 0.f);
            v.y = fmaxf(v.y + bb.y, 0.f);
            v.z = fmaxf(v.z + bb.z, 0.f);
            v.w = fmaxf(v.w + bb.w, 0.f);
        }
        *(float4*)(&xt[r][c4 * 4]) = v;
    }

    float acc[4][4] = {{0.f}};
#pragma unroll
    for (int kc = 0; kc < 4; ++kc) {
        __syncthreads();
#pragma unroll
        for (int i = 0; i < 4; ++i) {
            int f4 = t + i * 256;
            int r = f4 >> 5, c4 = f4 & 31;
            *(float4*)(&Wl[r][c4 * 4]) =
                *(const float4*)(W2 + (size_t)(kc * 32 + r) * 128 + c4 * 4);
        }
        __syncthreads();
#pragma unroll
        for (int k = 0; k < 32; ++k) {
            float4 w = *(const float4*)(&Wl[k][tc * 4]);
            float x0 = xt[tr * 4 + 0][kc * 32 + k];
            float x1 = xt[tr * 4 + 1][kc * 32 + k];
            float x2 = xt[tr * 4 + 2][kc * 32 + k];
            float x3 = xt[tr * 4 + 3][kc * 32 + k];
            acc[0][0] = fmaf(x0, w.x, acc[0][0]);
            acc[0][1] = fmaf(x0, w.y, acc[0][1]);
            acc[0][2] = fmaf(x0, w.z, acc[0][2]);
            acc[0][3] = fmaf(x0, w.w, acc[0][3]);
            acc[1][0] = fmaf(x1, w.x, acc[1][0]);
            acc[1][1] = fmaf(x1, w.y, acc[1][1]);
            acc[1][2] = fmaf(x1, w.z, acc[1][2]);
            acc[1][3] = fmaf(x1, w.w, acc[1][3]);
            acc[2][0] = fmaf(x2, w.x, acc[2][0]);
            acc[2][1] = fmaf(x2, w.y, acc[2][1]);
            acc[2][2] = fmaf(x2, w.z, acc[2][2]);
            acc[2][3] = fmaf(x2, w.w, acc[2][3]);
            acc[3][0] = fmaf(x3, w.x, acc[3][0]);
            acc[3][1] = fmaf(x3, w.y, acc[3][1]);
            acc[3][2] = fmaf(x3, w.z, acc[3][2]);
            acc[3][3] = fmaf(x3, w.w, acc[3][3]);
        }
    }

    float4 av = *(const float4*)(as2 + tc * 4);
    float4 dv = *(const float4*)(ad2 + tc * 4);
#pragma unroll
    for (int j = 0; j < 4; ++j) {
        int n = n0 + tr * 4 + j;
        float ps = acc[j][0] * av.x + acc[j][1] * av.y +
                   acc[j][2] * av.z + acc[j][3] * av.w;
        float pd = acc[j][0] * dv.x + acc[j][1] * dv.y +
                   acc[j][2] * dv.z + acc[j][3] * dv.w;
#pragma unroll
        for (int m = 16; m >= 1; m >>= 1) {
            ps += __shfl_xor(ps, m);
            pd += __shfl_xor(pd, m);
        }
        if (n < NN) {
            ushort4 hw;
            hw.x = f2bf(acc[j][0]); hw.y = f2bf(acc[j][1]);
            hw.z = f2bf(acc[j][2]); hw.w = f2bf(acc[j][3]);
            *(ushort4*)(h2bf + (size_t)n * 128 + tc * 4) = hw;
            if (tc == 0) { asrc[n] = ps; adst[n] = pd; }
        }
    }
}

// ---- layer2 gather-aggregate: heads=1 ----
__global__ __launch_bounds__(128) void k_agg2v(
        const int* __restrict__ off, const int* __restrict__ csr,
        const float* __restrict__ asrc, const float* __restrict__ adst,
        const u16* __restrict__ hbf, float* __restrict__ ob) {
    __shared__ float2 pair[DCAP2];
    __shared__ float red[4];
    int n = blockIdx.x, t = threadIdx.x;
    int e0 = off[n], deg = off[n + 1] - e0;
    float ad = adst[n];

    if (deg <= DCAP2) {
        float mymax = -1e30f;
        for (int e = t; e < deg; e += 128) {
            int s = csr[e0 + e];
            float al = lrelu(asrc[s] + ad);
            pair[e] = make_float2(al, __int_as_float(s));
            mymax = fmaxf(mymax, al);
        }
#pragma unroll
        for (int m = 32; m >= 1; m >>= 1) mymax = fmaxf(mymax, __shfl_xor(mymax, m));
        if ((t & 63) == 0) red[t >> 6] = mymax;
        __syncthreads();
        float amax = fmaxf(red[0], red[1]);
        float myden = 0.f;
        for (int e = t; e < deg; e += 128) {
            float ex = __expf(pair[e].x - amax);
            pair[e].x = ex;
            myden += ex;
        }
#pragma unroll
        for (int m = 32; m >= 1; m >>= 1) myden += __shfl_xor(myden, m);
        if ((t & 63) == 0) red[2 + (t >> 6)] = myden;
        __syncthreads();
        float inv = 1.f / (red[2] + red[3] + 1e-16f);
        const u16* hc = hbf + t;
        float acc = 0.f;
#pragma unroll 4
        for (int e = 0; e < deg; ++e) {
            float2 p = pair[e];
            acc = fmaf(p.x, bf2f(hc[(size_t)__float_as_int(p.y) * 128]), acc);
        }
        ob[(size_t)n * 128 + t] = acc * inv;
    } else {
        float amax = -1e30f;
        for (int e = e0; e < e0 + deg; ++e) {
            int s = csr[e];
            amax = fmaxf(amax, lrelu(asrc[s] + ad));
        }
        float den = 0.f, acc = 0.f;
        for (int e = e0; e < e0 + deg; ++e) {
            int s = csr[e];
            float ex = __expf(lrelu(asrc[s] + ad) - amax);
            den += ex;
            acc = fmaf(ex, bf2f(hbf[(size_t)s * 128 + t]), acc);
        }
        ob[(size_t)n * 128 + t] = acc / (den + 1e-16f);
    }
}

// ---- final: mean over nodes, d_out pre-set to b2 ----
__global__ __launch_bounds__(128) void k_final(const float* __restrict__ ob,
                                               float* __restrict__ out) {
    int c = threadIdx.x;
    float acc = 0.f;
    for (int n = blockIdx.x; n < NN; n += gridDim.x) acc += ob[n * 128 + c];
    atomicAdd(out + c, acc * (1.0f / NN));
}

extern "C" void kernel_launch(void* const* d_in, const int* in_sizes, int n_in,
                              void* d_out, int out_size, void* d_ws, size_t ws_size,
                              hipStream_t stream) {
    const float* x   = (const float*)d_in[0];
    const int*   ei  = (const int*)d_in[1];
    const float* W1  = (const float*)d_in[2];
    const float* as1 = (const float*)d_in[3];
    const float* ad1 = (const float*)d_in[4];
    const float* b1  = (const float*)d_in[5];
    const float* W2  = (const float*)d_in[6];
    const float* as2 = (const float*)d_in[7];
    const float* ad2 = (const float*)d_in[8];
    const float* b2  = (const float*)d_in[9];
    float* out = (float*)d_out;

    char* ws   = (char*)d_ws;
    u16*  hbf  = (u16*)ws;                               // NN*128 bf16
    float* ob  = (float*)(ws + (size_t)NN * 128 * 2);    // NN*128 f32
    float* asr1 = ob + (size_t)NN * 128;                 // NN*4
    float* adt1 = asr1 + NN * 4;                         // NN*4
    float* asr2 = adt1 + NN * 4;                         // NN
    float* adt2 = asr2 + NN;                             // NN
    int* deg    = (int*)(adt2 + NN);                     // NN
    int* off    = deg + NN;                              // NN+1
    int* cur    = off + NN + 1;                          // NN
    int* bsum   = cur + NN;                              // NBLK
    int* csr    = bsum + NBLK;                           // ET

    // CSR build (shared by both layers)
    k_init<<<(NN + 255) / 256, 256, 0, stream>>>(deg, b2, out);
    k_deg<<<(ET + 255) / 256, 256, 0, stream>>>(ei, deg);
    k_scan_a<<<NBLK, SCAN_B, 0, stream>>>(deg, off, bsum);
    k_scan_b<<<1, SCAN_B, 0, stream>>>(bsum, off);
    k_scan_c<<<NBLK, SCAN_B, 0, stream>>>(off, bsum, cur);
    k_fill<<<(ET + 255) / 256, 256, 0, stream>>>(ei, cur, csr);

    // layer 1
    k_node1<<<NN, 128, 0, stream>>>(x, W1, as1, ad1, hbf, asr1, adt1);
    k_agg1v<<<NN, 128, 0, stream>>>(off, csr, asr1, adt1, hbf, ob);

    // layer 2 (hbf reused for h2)
    k_node2t<<<(NN + 31) / 32, 256, 0, stream>>>(ob, b1, W2, as2, ad2, hbf, asr2, adt2);
    k_agg2v<<<NN, 128, 0, stream>>>(off, csr, asr2, adt2, hbf, ob);

    // mean pool (+b2 already in out)
    k_final<<<256, 128, 0, stream>>>(ob, out);
}

// Round 6
// 344.894 us; speedup vs baseline: 2.3036x; 2.3036x over previous
//
#include <hip/hip_runtime.h>

#define NN 50000
#define NE 800000
#define ET (NE + NN)   // 850000 edges incl. self-loops
#define SCAN_B 256
#define NBLK ((NN + SCAN_B - 1) / SCAN_B)   // 196
#define DCAP1 256      // max degree on fast path, layer1
#define DCAP2 512      // max degree on fast path, layer2

typedef unsigned short u16;
typedef unsigned int u32;

__device__ __forceinline__ float lrelu(float a) { return a > 0.f ? a : 0.2f * a; }
// f32 -> bf16 bits, round-to-nearest-even
__device__ __forceinline__ u16 f2bf(float f) {
    u32 b = __float_as_uint(f);
    b += 0x7FFFu + ((b >> 16) & 1u);
    return (u16)(b >> 16);
}
__device__ __forceinline__ float bf2f(u16 u) {
    return __uint_as_float(((u32)u) << 16);
}

// ---- init: zero degrees, d_out = b2 ----
__global__ void k_init(int* __restrict__ deg, const float* __restrict__ b2,
                       float* __restrict__ out) {
    int i = blockIdx.x * blockDim.x + threadIdx.x;
    if (i < NN)  deg[i] = 0;
    if (i < 128) out[i] = b2[i];
}

// ---- CSR build: degree count ----
__global__ void k_deg(const int* __restrict__ ei, int* __restrict__ deg) {
    int e = blockIdx.x * blockDim.x + threadIdx.x;
    if (e >= ET) return;
    int d = (e < NE) ? ei[NE + e] : e - NE;
    atomicAdd(deg + d, 1);
}

// ---- scan stage A ----
__global__ __launch_bounds__(SCAN_B) void k_scan_a(const int* __restrict__ deg,
                                                   int* __restrict__ off,
                                                   int* __restrict__ bsum) {
    __shared__ int sh[SCAN_B];
    int t = threadIdx.x, i = blockIdx.x * SCAN_B + t;
    int v = (i < NN) ? deg[i] : 0;
    sh[t] = v;
    __syncthreads();
#pragma unroll
    for (int s = 1; s < SCAN_B; s <<= 1) {
        int u = (t >= s) ? sh[t - s] : 0;
        __syncthreads();
        sh[t] += u;
        __syncthreads();
    }
    if (i < NN) off[i] = sh[t] - v;
    if (t == SCAN_B - 1) bsum[blockIdx.x] = sh[t];
}

// ---- scan stage B ----
__global__ __launch_bounds__(SCAN_B) void k_scan_b(int* __restrict__ bsum,
                                                   int* __restrict__ off) {
    __shared__ int sh[SCAN_B];
    int t = threadIdx.x;
    int v = (t < NBLK) ? bsum[t] : 0;
    sh[t] = v;
    __syncthreads();
#pragma unroll
    for (int s = 1; s < SCAN_B; s <<= 1) {
        int u = (t >= s) ? sh[t - s] : 0;
        __syncthreads();
        sh[t] += u;
        __syncthreads();
    }
    if (t < NBLK) bsum[t] = sh[t] - v;
    if (t == 0) off[NN] = ET;
}

// ---- scan stage C ----
__global__ __launch_bounds__(SCAN_B) void k_scan_c(int* __restrict__ off,
                                                   const int* __restrict__ bsum,
                                                   int* __restrict__ cur) {
    int i = blockIdx.x * SCAN_B + threadIdx.x;
    if (i >= NN) return;
    int o = off[i] + bsum[blockIdx.x];
    off[i] = o;
    cur[i] = o;
}

// ---- CSR fill ----
__global__ void k_fill(const int* __restrict__ ei, int* __restrict__ cur,
                       int* __restrict__ csr) {
    int e = blockIdx.x * blockDim.x + threadIdx.x;
    if (e >= ET) return;
    int s, d;
    if (e < NE) { s = ei[e]; d = ei[NE + e]; } else { s = d = e - NE; }
    int pos = atomicAdd(cur + d, 1);
    csr[pos] = s;
}

// ---- layer1 node transform: h1 = x@W1 (bf16 out) ; attention dots (f32) ----
__global__ __launch_bounds__(128) void k_node1(
        const float* __restrict__ x, const float* __restrict__ W1,
        const float* __restrict__ as1, const float* __restrict__ ad1,
        u16* __restrict__ hbf, float* __restrict__ asrc, float* __restrict__ adst) {
    int n = blockIdx.x, c = threadIdx.x;
    float x0 = x[2 * n], x1 = x[2 * n + 1];
    float hv = fmaf(x0, W1[c], x1 * W1[128 + c]);
    hbf[(size_t)n * 128 + c] = f2bf(hv);
    float ps = hv * as1[c], pd = hv * ad1[c];
#pragma unroll
    for (int m = 16; m >= 1; m >>= 1) {
        ps += __shfl_xor(ps, m);
        pd += __shfl_xor(pd, m);
    }
    if ((c & 31) == 0) {
        int hd = c >> 5;
        asrc[n * 4 + hd] = ps;
        adst[n * 4 + hd] = pd;
    }
}

// ---- layer1 gather-aggregate: edge-parallel softmax in LDS, heads=4 ----
__global__ __launch_bounds__(128) void k_agg1v(
        const int* __restrict__ off, const int* __restrict__ csr,
        const float* __restrict__ asrc, const float* __restrict__ adst,
        const u16* __restrict__ hbf, float* __restrict__ ob) {
    __shared__ float2 pair[4][DCAP1];      // {ex, src_bits}, [head][edge]
    __shared__ float redm[4], redd[4];
    int n = blockIdx.x, t = threadIdx.x;
    int hd = t >> 5, l = t & 31;
    int e0 = off[n], deg = off[n + 1] - e0;
    float ad = adst[n * 4 + hd];

    if (deg <= DCAP1) {
        float mymax = -1e30f;
        for (int e = l; e < deg; e += 32) {
            int s = csr[e0 + e];
            float al = lrelu(asrc[s * 4 + hd] + ad);
            pair[hd][e] = make_float2(al, __int_as_float(s));
            mymax = fmaxf(mymax, al);
        }
#pragma unroll
        for (int m = 16; m >= 1; m >>= 1) mymax = fmaxf(mymax, __shfl_xor(mymax, m));
        if (l == 0) redm[hd] = mymax;
        __syncthreads();
        float amax = redm[hd];
        float myden = 0.f;
        for (int e = l; e < deg; e += 32) {
            float ex = __expf(pair[hd][e].x - amax);
            pair[hd][e].x = ex;
            myden += ex;
        }
#pragma unroll
        for (int m = 16; m >= 1; m >>= 1) myden += __shfl_xor(myden, m);
        if (l == 0) redd[hd] = myden;
        __syncthreads();
        float inv = 1.f / (redd[hd] + 1e-16f);
        const u16* hc = hbf + t;
        float acc = 0.f;
#pragma unroll 4
        for (int e = 0; e < deg; ++e) {
            float2 p = pair[hd][e];
            acc = fmaf(p.x, bf2f(hc[(size_t)__float_as_int(p.y) * 128]), acc);
        }
        ob[(size_t)n * 128 + t] = acc * inv;
    } else {
        float amax = -1e30f;
        for (int e = e0; e < e0 + deg; ++e) {
            int s = csr[e];
            amax = fmaxf(amax, lrelu(asrc[s * 4 + hd] + ad));
        }
        float den = 0.f, acc = 0.f;
        for (int e = e0; e < e0 + deg; ++e) {
            int s = csr[e];
            float ex = __expf(lrelu(asrc[s * 4 + hd] + ad) - amax);
            den += ex;
            acc = fmaf(ex, bf2f(hbf[(size_t)s * 128 + t]), acc);
        }
        ob[(size_t)n * 128 + t] = acc / (den + 1e-16f);
    }
}

// ---- layer2 node transform, register-tiled GEMM, IN-PLACE over ob:
//      x2 = relu(ob+b1); h2 = x2@W2 stored back to ob (f32); attn dots.
//      Safe: each block reads only its own 32 rows, all reads precede writes.
__global__ __launch_bounds__(256) void k_node2t(
        float* ob, const float* __restrict__ b1,
        const float* __restrict__ W2, const float* __restrict__ as2,
        const float* __restrict__ ad2,
        float* __restrict__ asrc, float* __restrict__ adst) {
    __shared__ float Wl[32][128];
    __shared__ float xt[32][128];
    int t = threadIdx.x;
    int tc = t & 31, tr = t >> 5;
    int n0 = blockIdx.x * 32;

#pragma unroll
    for (int i = 0; i < 4; ++i) {
        int f4 = t + i * 256;
        int r = f4 >> 5, c4 = f4 & 31;
        float4 v = make_float4(0.f, 0.f, 0.f, 0.f);
        int n = n0 + r;
        if (n < NN) {
            v = *(const float4*)(ob + (size_t)n * 128 + c4 * 4);
            float4 bb = *(const float4*)(b1 + c4 * 4);
            v.x = fmaxf(v.x + bb.x, 0.f);
            v.y = fmaxf(v.y + bb.y, 0.f);
            v.z = fmaxf(v.z + bb.z, 0.f);
            v.w = fmaxf(v.w + bb.w, 0.f);
        }
        *(float4*)(&xt[r][c4 * 4]) = v;
    }

    float acc[4][4] = {{0.f}};
#pragma unroll
    for (int kc = 0; kc < 4; ++kc) {
        __syncthreads();
#pragma unroll
        for (int i = 0; i < 4; ++i) {
            int f4 = t + i * 256;
            int r = f4 >> 5, c4 = f4 & 31;
            *(float4*)(&Wl[r][c4 * 4]) =
                *(const float4*)(W2 + (size_t)(kc * 32 + r) * 128 + c4 * 4);
        }
        __syncthreads();
#pragma unroll
        for (int k = 0; k < 32; ++k) {
            float4 w = *(const float4*)(&Wl[k][tc * 4]);
            float x0 = xt[tr * 4 + 0][kc * 32 + k];
            float x1 = xt[tr * 4 + 1][kc * 32 + k];
            float x2 = xt[tr * 4 + 2][kc * 32 + k];
            float x3 = xt[tr * 4 + 3][kc * 32 + k];
            acc[0][0] = fmaf(x0, w.x, acc[0][0]);
            acc[0][1] = fmaf(x0, w.y, acc[0][1]);
            acc[0][2] = fmaf(x0, w.z, acc[0][2]);
            acc[0][3] = fmaf(x0, w.w, acc[0][3]);
            acc[1][0] = fmaf(x1, w.x, acc[1][0]);
            acc[1][1] = fmaf(x1, w.y, acc[1][1]);
            acc[1][2] = fmaf(x1, w.z, acc[1][2]);
            acc[1][3] = fmaf(x1, w.w, acc[1][3]);
            acc[2][0] = fmaf(x2, w.x, acc[2][0]);
            acc[2][1] = fmaf(x2, w.y, acc[2][1]);
            acc[2][2] = fmaf(x2, w.z, acc[2][2]);
            acc[2][3] = fmaf(x2, w.w, acc[2][3]);
            acc[3][0] = fmaf(x3, w.x, acc[3][0]);
            acc[3][1] = fmaf(x3, w.y, acc[3][1]);
            acc[3][2] = fmaf(x3, w.z, acc[3][2]);
            acc[3][3] = fmaf(x3, w.w, acc[3][3]);
        }
    }

    float4 av = *(const float4*)(as2 + tc * 4);
    float4 dv = *(const float4*)(ad2 + tc * 4);
#pragma unroll
    for (int j = 0; j < 4; ++j) {
        int n = n0 + tr * 4 + j;
        float ps = acc[j][0] * av.x + acc[j][1] * av.y +
                   acc[j][2] * av.z + acc[j][3] * av.w;
        float pd = acc[j][0] * dv.x + acc[j][1] * dv.y +
                   acc[j][2] * dv.z + acc[j][3] * dv.w;
#pragma unroll
        for (int m = 16; m >= 1; m >>= 1) {
            ps += __shfl_xor(ps, m);
            pd += __shfl_xor(pd, m);
        }
        if (n < NN) {
            *(float4*)(ob + (size_t)n * 128 + tc * 4) =
                make_float4(acc[j][0], acc[j][1], acc[j][2], acc[j][3]);
            if (tc == 0) { asrc[n] = ps; adst[n] = pd; }
        }
    }
}

// ---- f32 -> packed bf16 convert (h2 staging for the gather) ----
__global__ __launch_bounds__(256) void k_cvt(const float* __restrict__ in,
                                             u32* __restrict__ out) {
    int i = blockIdx.x * blockDim.x + threadIdx.x;   // pair index
    if (i >= NN * 64) return;
    float2 v = *(const float2*)(in + (size_t)i * 2);
    out[i] = (u32)f2bf(v.x) | ((u32)f2bf(v.y) << 16);
}

// ---- layer2 gather-aggregate: heads=1 ----
__global__ __launch_bounds__(128) void k_agg2v(
        const int* __restrict__ off, const int* __restrict__ csr,
        const float* __restrict__ asrc, const float* __restrict__ adst,
        const u16* __restrict__ hbf, float* __restrict__ ob) {
    __shared__ float2 pair[DCAP2];
    __shared__ float red[4];
    int n = blockIdx.x, t = threadIdx.x;
    int e0 = off[n], deg = off[n + 1] - e0;
    float ad = adst[n];

    if (deg <= DCAP2) {
        float mymax = -1e30f;
        for (int e = t; e < deg; e += 128) {
            int s = csr[e0 + e];
            float al = lrelu(asrc[s] + ad);
            pair[e] = make_float2(al, __int_as_float(s));
            mymax = fmaxf(mymax, al);
        }
#pragma unroll
        for (int m = 32; m >= 1; m >>= 1) mymax = fmaxf(mymax, __shfl_xor(mymax, m));
        if ((t & 63) == 0) red[t >> 6] = mymax;
        __syncthreads();
        float amax = fmaxf(red[0], red[1]);
        float myden = 0.f;
        for (int e = t; e < deg; e += 128) {
            float ex = __expf(pair[e].x - amax);
            pair[e].x = ex;
            myden += ex;
        }
#pragma unroll
        for (int m = 32; m >= 1; m >>= 1) myden += __shfl_xor(myden, m);
        if ((t & 63) == 0) red[2 + (t >> 6)] = myden;
        __syncthreads();
        float inv = 1.f / (red[2] + red[3] + 1e-16f);
        const u16* hc = hbf + t;
        float acc = 0.f;
#pragma unroll 4
        for (int e = 0; e < deg; ++e) {
            float2 p = pair[e];
            acc = fmaf(p.x, bf2f(hc[(size_t)__float_as_int(p.y) * 128]), acc);
        }
        ob[(size_t)n * 128 + t] = acc * inv;
    } else {
        float amax = -1e30f;
        for (int e = e0; e < e0 + deg; ++e) {
            int s = csr[e];
            amax = fmaxf(amax, lrelu(asrc[s] + ad));
        }
        float den = 0.f, acc = 0.f;
        for (int e = e0; e < e0 + deg; ++e) {
            int s = csr[e];
            float ex = __expf(lrelu(asrc[s] + ad) - amax);
            den += ex;
            acc = fmaf(ex, bf2f(hbf[(size_t)s * 128 + t]), acc);
        }
        ob[(size_t)n * 128 + t] = acc / (den + 1e-16f);
    }
}

// ---- final: mean over nodes, d_out pre-set to b2 ----
__global__ __launch_bounds__(128) void k_final(const float* __restrict__ ob,
                                               float* __restrict__ out) {
    int c = threadIdx.x;
    float acc = 0.f;
    for (int n = blockIdx.x; n < NN; n += gridDim.x) acc += ob[n * 128 + c];
    atomicAdd(out + c, acc * (1.0f / NN));
}

extern "C" void kernel_launch(void* const* d_in, const int* in_sizes, int n_in,
                              void* d_out, int out_size, void* d_ws, size_t ws_size,
                              hipStream_t stream) {
    const float* x   = (const float*)d_in[0];
    const int*   ei  = (const int*)d_in[1];
    const float* W1  = (const float*)d_in[2];
    const float* as1 = (const float*)d_in[3];
    const float* ad1 = (const float*)d_in[4];
    const float* b1  = (const float*)d_in[5];
    const float* W2  = (const float*)d_in[6];
    const float* as2 = (const float*)d_in[7];
    const float* ad2 = (const float*)d_in[8];
    const float* b2  = (const float*)d_in[9];
    float* out = (float*)d_out;

    char* ws   = (char*)d_ws;
    u16*  hbf  = (u16*)ws;                               // NN*128 bf16 (h1, then h2)
    float* ob  = (float*)(ws + (size_t)NN * 128 * 2);    // NN*128 f32 (out1/h2f/out2)
    float* asr1 = ob + (size_t)NN * 128;                 // NN*4
    float* adt1 = asr1 + NN * 4;                         // NN*4
    float* asr2 = adt1 + NN * 4;                         // NN
    float* adt2 = asr2 + NN;                             // NN
    int* deg    = (int*)(adt2 + NN);                     // NN
    int* off    = deg + NN;                              // NN+1
    int* cur    = off + NN + 1;                          // NN
    int* bsum   = cur + NN;                              // NBLK
    int* csr    = bsum + NBLK;                           // ET

    // CSR build (shared by both layers)
    k_init<<<(NN + 255) / 256, 256, 0, stream>>>(deg, b2, out);
    k_deg<<<(ET + 255) / 256, 256, 0, stream>>>(ei, deg);
    k_scan_a<<<NBLK, SCAN_B, 0, stream>>>(deg, off, bsum);
    k_scan_b<<<1, SCAN_B, 0, stream>>>(bsum, off);
    k_scan_c<<<NBLK, SCAN_B, 0, stream>>>(off, bsum, cur);
    k_fill<<<(ET + 255) / 256, 256, 0, stream>>>(ei, cur, csr);

    // layer 1
    k_node1<<<NN, 128, 0, stream>>>(x, W1, as1, ad1, hbf, asr1, adt1);
    k_agg1v<<<NN, 128, 0, stream>>>(off, csr, asr1, adt1, hbf, ob);

    // layer 2: GEMM in-place on ob, then convert to bf16 into hbf
    k_node2t<<<(NN + 31) / 32, 256, 0, stream>>>(ob, b1, W2, as2, ad2, asr2, adt2);
    k_cvt<<<(NN * 64 + 255) / 256, 256, 0, stream>>>(ob, (u32*)hbf);
    k_agg2v<<<NN, 128, 0, stream>>>(off, csr, asr2, adt2, hbf, ob);

    // mean pool (+b2 already in out)
    k_final<<<256, 128, 0, stream>>>(ob, out);
}